// Round 1
// baseline (417.885 us; speedup 1.0000x reference)
//
#include <hip/hip_runtime.h>
#include <math.h>

// Problem constants (from reference):
//   N = 1,000,000 user rows (u_V: N x 64)
//   M =   500,000 item rows (t_V: M x 64, b_V: M x 64)
//   P = N + 2M = 2,000,000 = len(x) = len(w_bias)
//   K = 64, GAMMA = (1,1,1,1)
#define N_U 1000000
#define M_T 500000
#define P_TOT (N_U + 2 * M_T)
#define KDIM 64

// Workspace layout (floats):
//   ws[0]        bias accumulator  (dot(x, w_bias))
//   ws[1]        sum_b_sq accumulator (xb . rownorms(b_V))
//   ws[8..71]    u_vec  (K)
//   ws[72..135]  t_vec  (K)
//   ws[136..199] sum_b  (K)
#define WS_BIAS 0
#define WS_SBSQ 1
#define WS_U 8
#define WS_T 72
#define WS_B 136
#define WS_FLOATS 256

__global__ void zero_ws_kernel(float* __restrict__ ws) {
    int i = threadIdx.x;
    if (i < WS_FLOATS) ws[i] = 0.0f;
}

// Sparsity-aware accumulate: every term of the FM is linear in x's entries,
// so zero entries contribute exactly zero — skipping them is exact for any x
// with finite weights. Scan x vectorized (float4), gather V-rows only at
// nonzeros (66 in the test input).
__global__ void scan_accum_kernel(const float* __restrict__ x,
                                  const float* __restrict__ w_bias,
                                  const float* __restrict__ u_V,
                                  const float* __restrict__ t_V,
                                  const float* __restrict__ b_V,
                                  float* __restrict__ ws,
                                  int P) {
    int gid = blockIdx.x * blockDim.x + threadIdx.x;
    long long base = (long long)gid * 4;
    if (base >= P) return;

    float4 v = *reinterpret_cast<const float4*>(x + base);
    float vals[4] = {v.x, v.y, v.z, v.w};

#pragma unroll
    for (int j = 0; j < 4; ++j) {
        long long i = base + j;
        if (i >= P) break;
        float xv = vals[j];
        if (xv != 0.0f) {
            // bias term
            atomicAdd(&ws[WS_BIAS], xv * w_bias[i]);
            // pick the V matrix + accumulator for this region of x
            const float* row;
            float* acc;
            bool is_b = false;
            if (i < N_U) {
                row = u_V + i * KDIM;
                acc = ws + WS_U;
            } else if (i < (long long)N_U + M_T) {
                row = t_V + (i - N_U) * KDIM;
                acc = ws + WS_T;
            } else {
                row = b_V + (i - N_U - M_T) * KDIM;
                acc = ws + WS_B;
                is_b = true;
            }
            float nrm = 0.0f;
#pragma unroll
            for (int k = 0; k < KDIM; ++k) {
                float rv = row[k];
                atomicAdd(&acc[k], xv * rv);
                nrm += rv * rv;
            }
            if (is_b) atomicAdd(&ws[WS_SBSQ], xv * nrm);
        }
    }
}

// One wave: four K=64 dot products via shuffle reduction, then sigmoid.
__global__ void finalize_kernel(const float* __restrict__ ws,
                                const float* __restrict__ w0,
                                const float* __restrict__ delta,
                                float* __restrict__ out) {
    int k = threadIdx.x;  // 0..63
    float u = ws[WS_U + k];
    float t = ws[WS_T + k];
    float b = ws[WS_B + k];

    float ut = u * t;  // -> dot(u_vec, t_vec)
    float tb = t * b;  // -> dot(t_vec, sum_b)
    float bb = b * b;  // -> dot(sum_b, sum_b)
    float ub = u * b;  // -> dot(u_vec, sum_b)

#pragma unroll
    for (int off = 32; off > 0; off >>= 1) {
        ut += __shfl_down(ut, off);
        tb += __shfl_down(tb, off);
        bb += __shfl_down(bb, off);
        ub += __shfl_down(ub, off);
    }

    if (k == 0) {
        float bias = ws[WS_BIAS];
        float sbsq = ws[WS_SBSQ];
        float bs = 0.5f * (bb - sbsq);
        // GAMMA = (1,1,1,1)
        float y = w0[0] + bias + ut + tb + bs + ub;
        float z = y * delta[0];
        out[0] = 1.0f / (1.0f + expf(-z));
    }
}

extern "C" void kernel_launch(void* const* d_in, const int* in_sizes, int n_in,
                              void* d_out, int out_size, void* d_ws, size_t ws_size,
                              hipStream_t stream) {
    // setup_inputs() order: x, delta, pmi, w_0, w_bias, u_V, t_V, b_V
    const float* x      = (const float*)d_in[0];
    const float* delta  = (const float*)d_in[1];
    // d_in[2] = pmi (unused by reference)
    const float* w0     = (const float*)d_in[3];
    const float* w_bias = (const float*)d_in[4];
    const float* u_V    = (const float*)d_in[5];
    const float* t_V    = (const float*)d_in[6];
    const float* b_V    = (const float*)d_in[7];
    float* out = (float*)d_out;
    float* ws  = (float*)d_ws;

    int P = in_sizes[0];  // 2,000,000

    hipLaunchKernelGGL(zero_ws_kernel, dim3(1), dim3(256), 0, stream, ws);

    int nvec = (P + 3) / 4;              // float4 lanes
    int blocks = (nvec + 255) / 256;     // ~1954 blocks
    hipLaunchKernelGGL(scan_accum_kernel, dim3(blocks), dim3(256), 0, stream,
                       x, w_bias, u_V, t_V, b_V, ws, P);

    hipLaunchKernelGGL(finalize_kernel, dim3(1), dim3(64), 0, stream,
                       ws, w0, delta, out);
}